// Round 6
// baseline (409.591 us; speedup 1.0000x reference)
//
#include <hip/hip_runtime.h>
#include <math.h>

#define NUM_LAYERS 3
#define KCB 2048        // codebook size
#define DIM 256         // embed dim
#define NROWS 32768     // B*T
#define NQ (NROWS * DIM)

// d_ws layout: F = fp16 codebook fragments (16x16x32 layout, verified).
//   tile tn (16 cw) = 16384 B = 8 kb-blocks of [hi 1024 B | lo 1024 B]
//   within a 1024 B half: lane*16 B -> 8 halves: W[tn*16+(lane&15)][kb*32+(lane>>4)*8+j]
//   layer stride 2 MB. wsq (fp32 ||w||^2, 3*2048) at byte offset F_BYTES.
//   chunk c = 32 KB = tiles {2c, 2c+1} at Fb + c*32768.
#define F_BYTES (3u * 128u * 16384u)   // 6,291,456

// dynamic LDS partition (bytes) -- no exchange buffer needed (full-K waves)
#define BSH_OFF  0        // 2 bufs x 32768 (one 32-cw chunk each)
#define BV_OFF   65536    // 8 waves x 32 rows f32 = 1024
#define BI_OFF   66560    // 8 x 32 i32 = 1024
#define BIDX_OFF 67584    // 128 i32 = 512
#define SMEM_BYTES 68096

typedef _Float16 half8 __attribute__((ext_vector_type(8)));
typedef float   f32x4 __attribute__((ext_vector_type(4)));

// ---------------- prep: ||w||^2 (unchanged, verified) ----------------
__global__ void rvq_wsq(const float* __restrict__ cb, float* __restrict__ wsq)
{
    int tid = blockIdx.x * 256 + threadIdx.x;   // 0 .. 6143
    const float* p = cb + (size_t)tid * DIM;
    float s = 0.f;
    #pragma unroll
    for (int u = 0; u < 64; ++u) {
        float4 v = *(const float4*)(p + u * 4);
        s = fmaf(v.x, v.x, s); s = fmaf(v.y, v.y, s);
        s = fmaf(v.z, v.z, s); s = fmaf(v.w, v.w, s);
    }
    wsq[tid] = s;
}

// ---------------- prep: fp16 hi/lo fragment repack (unchanged, verified) ----------------
__global__ void rvq_repack(const float* __restrict__ cb, unsigned short* __restrict__ F)
{
    int b = blockIdx.x;           // layer*1024 + tn*8 + kb
    int layer = b >> 10;
    int rem   = b & 1023;
    int tn    = rem >> 3;
    int kb    = rem & 7;
    int lane  = threadIdx.x;

    int cw = tn * 16 + (lane & 15);
    int k0 = kb * 32 + (lane >> 4) * 8;
    const float* src = cb + ((size_t)(layer * KCB + cw)) * DIM + k0;
    float4 x0 = *(const float4*)(src);
    float4 x1 = *(const float4*)(src + 4);
    float v[8] = {x0.x, x0.y, x0.z, x0.w, x1.x, x1.y, x1.z, x1.w};

    half8 hi, lo;
    #pragma unroll
    for (int j = 0; j < 8; ++j) {
        _Float16 h = (_Float16)v[j];
        hi[j] = h;
        lo[j] = (_Float16)(v[j] - (float)h);
    }
    size_t base = ((size_t)b) * 1024;   // ushort units (2048 B per (layer,tn,kb))
    *(half8*)(F + base + lane * 8)        = hi;
    *(half8*)(F + base + 512 + lane * 8)  = lo;
}

// ---------------- async stage of one 32 KB chunk (512 threads) ----------------
__device__ __forceinline__ void stage_chunk32(const char* Fb, char* dst, int c, int t)
{
    const char* g = Fb + (size_t)c * 32768;
    #pragma unroll
    for (int i = 0; i < 4; ++i) {
        int off = (i * 512 + t) * 16;
        __builtin_amdgcn_global_load_lds(
            (const __attribute__((address_space(1))) unsigned int*)(g + off),
            (__attribute__((address_space(3))) unsigned int*)(dst + off), 16, 0, 0);
    }
}

// ---------------- full cross for one 16-cw tile over full K (256) ----------------
// 1-step register prefetch + sched_group_barrier pins ({DS_READ x2, MFMA x6})
// interleave the LDS pipe with the matrix pipe (R4: +7%). 4-acc rotation keeps
// dependent MFMAs on the same acc >= 4 issue slots apart. ALL indices static.
__device__ __forceinline__ void tile_full_pl(
    const char* tbase, const half8 (&ahi)[2][8], const half8 (&alo)[2][8],
    int lane, f32x4 (&po)[2])
{
    const f32x4 z = {0.f, 0.f, 0.f, 0.f};
    f32x4 a00 = z, a01 = z, a10 = z, a11 = z;
    const char* p = tbase + lane * 16;
    half8 bhi = *(const half8*)(p);
    half8 blo = *(const half8*)(p + 1024);
    #pragma unroll
    for (int kb = 0; kb < 8; ++kb) {
        half8 nhi, nlo;
        if (kb < 7) {
            nhi = *(const half8*)(p + (kb + 1) * 2048);
            nlo = *(const half8*)(p + (kb + 1) * 2048 + 1024);
            __builtin_amdgcn_sched_group_barrier(0x100, 2, 0);   // 2 DS_READ
        }
        if (kb & 1) {
            a01 = __builtin_amdgcn_mfma_f32_16x16x32_f16(ahi[0][kb], bhi, a01, 0, 0, 0);
            a11 = __builtin_amdgcn_mfma_f32_16x16x32_f16(ahi[1][kb], bhi, a11, 0, 0, 0);
            a00 = __builtin_amdgcn_mfma_f32_16x16x32_f16(alo[0][kb], bhi, a00, 0, 0, 0);
            a10 = __builtin_amdgcn_mfma_f32_16x16x32_f16(alo[1][kb], bhi, a10, 0, 0, 0);
            a01 = __builtin_amdgcn_mfma_f32_16x16x32_f16(ahi[0][kb], blo, a01, 0, 0, 0);
            a11 = __builtin_amdgcn_mfma_f32_16x16x32_f16(ahi[1][kb], blo, a11, 0, 0, 0);
        } else {
            a00 = __builtin_amdgcn_mfma_f32_16x16x32_f16(ahi[0][kb], bhi, a00, 0, 0, 0);
            a10 = __builtin_amdgcn_mfma_f32_16x16x32_f16(ahi[1][kb], bhi, a10, 0, 0, 0);
            a01 = __builtin_amdgcn_mfma_f32_16x16x32_f16(alo[0][kb], bhi, a01, 0, 0, 0);
            a11 = __builtin_amdgcn_mfma_f32_16x16x32_f16(alo[1][kb], bhi, a11, 0, 0, 0);
            a00 = __builtin_amdgcn_mfma_f32_16x16x32_f16(ahi[0][kb], blo, a00, 0, 0, 0);
            a10 = __builtin_amdgcn_mfma_f32_16x16x32_f16(ahi[1][kb], blo, a10, 0, 0, 0);
        }
        __builtin_amdgcn_sched_group_barrier(0x8, 6, 0);         // 6 MFMA
        if (kb < 7) { bhi = nhi; blo = nlo; }
    }
    #pragma unroll
    for (int i = 0; i < 4; ++i) { po[0][i] = a00[i] + a01[i]; po[1][i] = a10[i] + a11[i]; }
}

// ---------------- final-layer store, MI as a COMPILE-TIME index ----------------
// (rule #20 fix: R1's `ahi[mi][ct*4+kq]` runtime index demoted the whole
// fragment file to scratch -> 216 MB spill traffic. MI is now a template arg.)
template<int MI>
__device__ __forceinline__ void final_store(
    const float* __restrict__ h, const float* __restrict__ Wl,
    float* __restrict__ out, const int* __restrict__ bidx_sh,
    const half8 (&ahi)[2][8], const half8 (&alo)[2][8],
    int row0w, int rg, int arow, int aq)
{
    const int row = row0w + MI * 16 + arow;
    const int bi  = bidx_sh[rg * 32 + MI * 16 + arow];
    const float* wrow = Wl + (size_t)bi * DIM;
    #pragma unroll
    for (int kb = 0; kb < 8; ++kb) {
        const int ko = kb * 32 + aq * 8;
        const float* wp = wrow + ko;
        const float* hp = h + (size_t)row * DIM + ko;
        float4 w0 = *(const float4*)(wp);
        float4 w1 = *(const float4*)(wp + 4);
        float4 h0 = *(const float4*)(hp);
        float4 h1 = *(const float4*)(hp + 4);
        float wv8[8] = {w0.x, w0.y, w0.z, w0.w, w1.x, w1.y, w1.z, w1.w};
        float hv8[8] = {h0.x, h0.y, h0.z, h0.w, h1.x, h1.y, h1.z, h1.w};
        float o[8];
        #pragma unroll
        for (int j = 0; j < 8; ++j) {
            float r = ((float)ahi[MI][kb][j] + (float)alo[MI][kb][j]) - wv8[j];
            o[j] = hv8[j] - r;
        }
        float* op = out + (size_t)row * DIM + ko;
        *(float4*)(op)     = make_float4(o[0], o[1], o[2], o[3]);
        *(float4*)(op + 4) = make_float4(o[4], o[5], o[6], o[7]);
    }
}

// ---------------- main fused RVQ ----------------
// 512 thr = 8 waves: wave = rg(0..3)*2 + ct(0..1). 128 rows/block, grid 256,
// 1 block/CU, 2 waves/SIMD. FULL-K fragments per wave (128 VGPRs; budget 256
// via waves_per_eu(2,2)) -> wave's tile dot-product completes in-wave: NO
// exchange, no mid-chunk dependency, ONE barrier per chunk. rsq dropped (a
// per-row constant cannot change the argmin). wq prefetched 1 chunk ahead so
// no global-load latency sits in front of the vmcnt(0) barrier.
__global__ __attribute__((amdgpu_flat_work_group_size(512, 512), amdgpu_waves_per_eu(2, 2)))
void rvq_main(const float* __restrict__ h,
              const float* __restrict__ cb,
              const unsigned short* __restrict__ F,
              const float* __restrict__ wsq,
              float* __restrict__ out)
{
    extern __shared__ char smem[];
    char*  Bsh     = smem + BSH_OFF;
    float* bV_sh   = (float*)(smem + BV_OFF);
    int*   bI_sh   = (int*)  (smem + BI_OFF);
    int*   bidx_sh = (int*)  (smem + BIDX_OFF);

    const int t     = threadIdx.x;
    const int lane  = t & 63;
    const int wv    = t >> 6;         // 0..7
    const int ct    = wv & 1;         // tile team: tile (2c+ct) of chunk c
    const int rg    = wv >> 1;        // row group (32 rows each)
    const int rowB  = blockIdx.x * 128;
    const int row0w = rowB + rg * 32;
    const int arow  = lane & 15;      // A row / C col
    const int aq    = lane >> 4;      // k-quad / C row-quad

    // ---- residual fragments (fp16 hi/lo, FULL K) ----
    half8 ahi[2][8], alo[2][8];
    #pragma unroll
    for (int mi = 0; mi < 2; ++mi) {
        #pragma unroll
        for (int kb = 0; kb < 8; ++kb) {
            const float* p = h + (size_t)(row0w + mi * 16 + arow) * DIM + kb * 32 + aq * 8;
            float4 x0 = *(const float4*)(p);
            float4 x1 = *(const float4*)(p + 4);
            float v[8] = {x0.x, x0.y, x0.z, x0.w, x1.x, x1.y, x1.z, x1.w};
            #pragma unroll
            for (int j = 0; j < 8; ++j) {
                _Float16 hv = (_Float16)v[j];
                ahi[mi][kb][j] = hv;
                alo[mi][kb][j] = (_Float16)(v[j] - (float)hv);
            }
        }
    }

    // ---- prefetch layer 0, chunk 0 into buf 0 ----
    stage_chunk32((const char*)F, Bsh, 0, t);

    for (int l = 0; l < NUM_LAYERS; ++l) {
        const float* __restrict__ Wl  = cb + (size_t)l * KCB * DIM;
        const float* __restrict__ wql = wsq + l * KCB;
        const char*  Fb = (const char*)F + (size_t)l * 2097152;

        // wq for chunk 0 (hidden under the layer-entry barrier)
        float wq_cur = wql[ct * 16 + arow];

        // layer entry: chunk-0 staging landed, all waves aligned
        asm volatile("s_waitcnt vmcnt(0)" ::: "memory");
        __builtin_amdgcn_sched_barrier(0);
        __builtin_amdgcn_s_barrier();

        float bestV[2][4];
        int   bestI[2][4];
        #pragma unroll
        for (int mi = 0; mi < 2; ++mi)
            #pragma unroll
            for (int i = 0; i < 4; ++i) { bestV[mi][i] = INFINITY; bestI[mi][i] = 0; }

        // ---- 64 chunks of 32 cw; wave computes FULL cross of tile 2c+ct ----
        for (int c = 0; c < 64; ++c) {
            const int cur = c & 1;
            float wq_next = 0.f;
            if (c < 63) {
                wq_next = wql[(c + 1) * 32 + ct * 16 + arow];   // hidden: used next chunk
                stage_chunk32(Fb, Bsh + (size_t)(1 - cur) * 32768, c + 1, t);
            }

            f32x4 po[2];
            __builtin_amdgcn_s_setprio(1);
            tile_full_pl(Bsh + (size_t)cur * 32768 + (size_t)ct * 16384, ahi, alo, lane, po);
            __builtin_amdgcn_s_setprio(0);

            const int col = c * 32 + ct * 16 + arow;
            #pragma unroll
            for (int i = 0; i < 4; ++i) {
                float d0 = fmaf(-2.f, po[0][i], wq_cur);
                if (d0 < bestV[0][i]) { bestV[0][i] = d0; bestI[0][i] = col; }
                float d1 = fmaf(-2.f, po[1][i], wq_cur);
                if (d1 < bestV[1][i]) { bestV[1][i] = d1; bestI[1][i] = col; }
            }
            wq_cur = wq_next;

            // single barrier: our B-reads consumed (lgkm implicit via MFMA use);
            // next-chunk staging landed (vmcnt(0), issued a full chunk ago).
            asm volatile("s_waitcnt vmcnt(0)" ::: "memory");
            __builtin_amdgcn_sched_barrier(0);
            __builtin_amdgcn_s_barrier();
        }

        // ---- argmin: reduce across the 16 arow-lanes sharing each row-quad ----
        #pragma unroll
        for (int mi = 0; mi < 2; ++mi)
            #pragma unroll
            for (int i = 0; i < 4; ++i) {
                float bv = bestV[mi][i]; int bi = bestI[mi][i];
                #pragma unroll
                for (int s = 8; s; s >>= 1) {
                    float ov = __shfl_xor(bv, s, 16);
                    int   oi = __shfl_xor(bi, s, 16);
                    if (ov < bv || (ov == bv && oi < bi)) { bv = ov; bi = oi; }
                }
                bestV[mi][i] = bv; bestI[mi][i] = bi;
            }
        if (arow == 0) {
            #pragma unroll
            for (int mi = 0; mi < 2; ++mi)
                #pragma unroll
                for (int i = 0; i < 4; ++i) {
                    bV_sh[wv * 32 + mi * 16 + aq * 4 + i] = bestV[mi][i];
                    bI_sh[wv * 32 + mi * 16 + aq * 4 + i] = bestI[mi][i];
                }
        }
        __syncthreads();

        // ---- combine the two ct-teams' col-halves per row, write index ----
        if (t < 128) {
            int rgi = t >> 5, rl = t & 31;
            float v0 = bV_sh[(rgi * 2 + 0) * 32 + rl]; int i0 = bI_sh[(rgi * 2 + 0) * 32 + rl];
            float v1 = bV_sh[(rgi * 2 + 1) * 32 + rl]; int i1 = bI_sh[(rgi * 2 + 1) * 32 + rl];
            int bi = (v1 < v0 || (v1 == v0 && i1 < i0)) ? i1 : i0;
            bidx_sh[t] = bi;
            out[NQ + (size_t)l * NROWS + rowB + t] = (float)bi;
        }
        // prefetch next layer's chunk 0 (independent of bidx) into buf 0
        if (l < NUM_LAYERS - 1)
            stage_chunk32(Fb + 2097152, Bsh, 0, t);
        __syncthreads();   // bidx_sh visible

        if (l < NUM_LAYERS - 1) {
            // ---- residual update in registers: r <- (hi+lo) - w, re-split ----
            // (all indices static: mi, kb are unrolled literals)
            #pragma unroll
            for (int mi = 0; mi < 2; ++mi) {
                const int bi = bidx_sh[rg * 32 + mi * 16 + arow];
                const float* wrow = Wl + (size_t)bi * DIM;
                #pragma unroll
                for (int kb = 0; kb < 8; ++kb) {
                    const float* wp = wrow + kb * 32 + aq * 8;
                    float4 w0 = *(const float4*)(wp);
                    float4 w1 = *(const float4*)(wp + 4);
                    float wv8[8] = {w0.x, w0.y, w0.z, w0.w, w1.x, w1.y, w1.z, w1.w};
                    #pragma unroll
                    for (int j = 0; j < 8; ++j) {
                        float r = ((float)ahi[mi][kb][j] + (float)alo[mi][kb][j]) - wv8[j];
                        _Float16 hv = (_Float16)r;
                        ahi[mi][kb][j] = hv;
                        alo[mi][kb][j] = (_Float16)(r - (float)hv);
                    }
                }
            }
        } else {
            // ---- final: out = h - (r2 - w3); ct teams split the row-halves ----
            if (ct == 0) final_store<0>(h, Wl, out, bidx_sh, ahi, alo, row0w, rg, arow, aq);
            else         final_store<1>(h, Wl, out, bidx_sh, ahi, alo, row0w, rg, arow, aq);
        }
    }
}

extern "C" void kernel_launch(void* const* d_in, const int* in_sizes, int n_in,
                              void* d_out, int out_size, void* d_ws, size_t ws_size,
                              hipStream_t stream) {
    const float* h  = (const float*)d_in[0];
    const float* cb = (const float*)d_in[1];
    float* out = (float*)d_out;
    unsigned short* F = (unsigned short*)d_ws;
    float* wsq = (float*)((char*)d_ws + F_BYTES);

    hipFuncSetAttribute((const void*)rvq_main,
                        hipFuncAttributeMaxDynamicSharedMemorySize, SMEM_BYTES);

    rvq_wsq   <<<dim3(24),   dim3(256), 0, stream>>>(cb, wsq);
    rvq_repack<<<dim3(3072), dim3(64),  0, stream>>>(cb, F);
    rvq_main  <<<dim3(NROWS / 128), dim3(512), SMEM_BYTES, stream>>>(h, cb, F, wsq, out);
}